// Round 16
// baseline (374.117 us; speedup 1.0000x reference)
//
#include <hip/hip_runtime.h>

#define TOK 2048
#define DIM 1024
#define HID 4096
#define NE 8
#define KSPLIT 4
#define T2MAX 16

typedef unsigned short u16;
typedef __attribute__((ext_vector_type(8))) short s16x8;
typedef __attribute__((ext_vector_type(4))) short s16x4;
typedef __attribute__((ext_vector_type(4))) float f32x4;

__device__ __forceinline__ u16 f2b(float f) {
  unsigned u = __builtin_bit_cast(unsigned, f);
  unsigned r = (u + 0x7fffu + ((u >> 16) & 1u)) >> 16;
  return (u16)r;
}

__device__ __forceinline__ void gld_lds16(const void* g, void* l) {
  __builtin_amdgcn_global_load_lds((const __attribute__((address_space(1))) void*)g,
                                   (__attribute__((address_space(3))) void*)l, 16, 0, 0);
}

// ---------------- gating: one wave per token (512 blocks) ----------------
__global__ __launch_bounds__(256) void k_gate(const float* __restrict__ x,
    const float* __restrict__ noise, const float* __restrict__ gw,
    const float* __restrict__ nw,
    int* __restrict__ tok_e, float* __restrict__ tok_w,
    int* __restrict__ bhist, float* __restrict__ bgw, u16* __restrict__ x16) {
  const int wid = threadIdx.x >> 6, lane = threadIdx.x & 63;
  const int t = blockIdx.x * 4 + wid;
  const float* xr = x + (size_t)t * DIM + lane * 16;
  float acc[NE];
#pragma unroll
  for (int e = 0; e < NE; ++e) acc[e] = 0.f;
  u16 xb[16];
#pragma unroll
  for (int j = 0; j < 4; ++j) {
    float4 xv = *(const float4*)(xr + j * 4);
    xb[j * 4 + 0] = f2b(xv.x); xb[j * 4 + 1] = f2b(xv.y);
    xb[j * 4 + 2] = f2b(xv.z); xb[j * 4 + 3] = f2b(xv.w);
#pragma unroll
    for (int e = 0; e < NE; ++e) {
      float4 gv = *(const float4*)(gw + e * DIM + lane * 16 + j * 4);
      acc[e] += xv.x * gv.x + xv.y * gv.y + xv.z * gv.z + xv.w * gv.w;
    }
  }
  *(s16x8*)(x16 + (size_t)t * DIM + lane * 16) = *(const s16x8*)xb;
  *(s16x8*)(x16 + (size_t)t * DIM + lane * 16 + 8) = *(const s16x8*)(xb + 8);
#pragma unroll
  for (int e = 0; e < NE; ++e) {
#pragma unroll
    for (int off = 32; off >= 1; off >>= 1) acc[e] += __shfl_xor(acc[e], off);
  }
  float m = acc[0];
#pragma unroll
  for (int e = 1; e < NE; ++e) m = fmaxf(m, acc[e]);
  float p[NE]; float s = 0.f;
#pragma unroll
  for (int e = 0; e < NE; ++e) { p[e] = expf(acc[e] - m); s += p[e]; }
  float inv = 1.f / s;
  float v[NE];
#pragma unroll
  for (int e = 0; e < NE; ++e) v[e] = acc[e] + noise[t * NE + e] * nw[e];
  float v0 = -3.4e38f, v1 = -3.4e38f; int i0 = 0, i1 = 0;
#pragma unroll
  for (int e = 0; e < NE; ++e) {
    float ve = v[e];
    if (ve > v0) { v1 = v0; i1 = i0; v0 = ve; i0 = e; }
    else if (ve > v1) { v1 = ve; i1 = e; }
  }
  float e1 = expf(v1 - v0);
  float den = 1.f + e1;
  float w0 = 1.f / den, w1v = e1 / den;

  __shared__ float pl[4][NE];
  __shared__ int el[4][2];
  if (lane == 0) {
#pragma unroll
    for (int e = 0; e < NE; ++e) pl[wid][e] = p[e] * inv;
    el[wid][0] = i0; el[wid][1] = i1;
    tok_e[t * 2] = i0; tok_e[t * 2 + 1] = i1;
    tok_w[t * 2] = w0; tok_w[t * 2 + 1] = w1v;
  }
  __syncthreads();
  if (threadIdx.x < NE) {
    const int e = threadIdx.x;
    float ps = pl[0][e] + pl[1][e] + pl[2][e] + pl[3][e];
    int h = 0;
#pragma unroll
    for (int j = 0; j < 4; ++j) {
      h += (el[j][0] == e);
      h += (el[j][1] == e);
    }
    bgw[blockIdx.x * NE + e] = ps;
    bhist[blockIdx.x * NE + e] = h;
  }
}

// ---------------- scan: offsets, counts, prefix, 512-row tile table, lb loss ----------------
__global__ __launch_bounds__(512) void k_scan(const int* __restrict__ bhist,
    const float* __restrict__ bgw, int* __restrict__ blk_off, int* __restrict__ prefix,
    int* __restrict__ counts, int* __restrict__ tile_tab, float* __restrict__ loss_out) {
  const int i = threadIdx.x, lane = i & 63, wv = i >> 6;
  __shared__ int wsum[8];
  __shared__ float wfs[8];
  __shared__ int etot[8];
  __shared__ float fsum[8];
  for (int e = 0; e < NE; ++e) {
    int v = bhist[i * NE + e];
    int sc = v;
#pragma unroll
    for (int off = 1; off < 64; off <<= 1) {
      int u = __shfl_up(sc, off);
      if (lane >= off) sc += u;
    }
    float f = bgw[i * NE + e];
#pragma unroll
    for (int off = 32; off >= 1; off >>= 1) f += __shfl_xor(f, off);
    if (lane == 63) wsum[wv] = sc;
    if (lane == 0) wfs[wv] = f;
    __syncthreads();
    int base = 0;
    for (int w2 = 0; w2 < wv; ++w2) base += wsum[w2];
    blk_off[i * NE + e] = base + sc - v;
    if (i == 0) {
      float tf = 0.f;
      for (int w2 = 0; w2 < 8; ++w2) tf += wfs[w2];
      fsum[e] = tf;
    }
    if (i == 511) etot[e] = base + sc;
    __syncthreads();
  }
  if (i == 0) {
    int sacc = 0;
    float l = 0.f;
    int tt = 0;
#pragma unroll
    for (int e = 0; e < NE; ++e) { prefix[e] = sacc; counts[e] = etot[e]; sacc += etot[e]; }
    for (int e = 0; e < NE; ++e) {
      const int nmt = (etot[e] + 511) >> 9;
      for (int m2 = 0; m2 < nmt && tt < T2MAX; ++m2) tile_tab[tt++] = (e << 16) | m2;
    }
    for (; tt < T2MAX; ++tt) tile_tab[tt] = -1;
#pragma unroll
    for (int e = 0; e < NE; ++e) {
      float d = fsum[e] * (1.f / TOK) - 0.125f;
      l += d * d;
    }
    *loss_out = l * (0.01f / NE);
  }
}

// ---------------- build compacted expert lists + inverse map ----------------
__global__ __launch_bounds__(256) void k_build(const int* __restrict__ tok_e,
    const float* __restrict__ tok_w, const int* __restrict__ prefix,
    const int* __restrict__ blk_off, int* __restrict__ ent, float* __restrict__ entw,
    int* __restrict__ inv) {
  const int t = blockIdx.x * 256 + threadIdx.x;
  const int g = t >> 2;
  const int base = (t & 3) * 2;
  int ee[8];
#pragma unroll
  for (int j = 0; j < 8; ++j) ee[j] = tok_e[g * 8 + j];
#pragma unroll
  for (int s = 0; s < 2; ++s) {
    const int e = ee[base + s];
    int rank = 0;
#pragma unroll
    for (int j = 0; j < 8; ++j) rank += (j < base + s) && (ee[j] == e);
    const int idx = prefix[e] + blk_off[g * NE + e] + rank;
    ent[idx] = t * 2 + s;
    entw[idx] = tok_w[t * 2 + s];
    inv[t * 2 + s] = idx;
  }
}

// ====== GEMM1: 512x64 tile, weights once, XCD-pinned (tile -> XCD tile%8) ======
// grid: 1024 flat blocks. b&7 = XCD slot; decode nt 0..63, tile 0..15.
__global__ __launch_bounds__(512) void k_gemm1f(const u16* __restrict__ x16,
    const float* __restrict__ w1, const float* __restrict__ w2,
    const float* __restrict__ b1, const float* __restrict__ b2,
    const int* __restrict__ ent, const int* __restrict__ counts,
    const int* __restrict__ prefix, const int* __restrict__ tile_tab,
    u16* __restrict__ act) {
  const int bfl = blockIdx.x;
  const int xcd = bfl & 7;
  const int k2 = bfl >> 3;        // 0..127
  const int nt = k2 & 63;         // 0..63
  const int th = k2 >> 6;         // 0..1
  const int tile = th * 8 + xcd;  // 0..15 ; all 64 panels of a tile share an XCD
  const int tt = tile_tab[tile];
  if (tt < 0) return;
  const int e = tt >> 16, mt = tt & 0xffff;
  const int cnt = counts[e];
  const int pfx = prefix[e];
  const int tid = threadIdx.x, w = tid >> 6, l = tid & 63;

  __shared__ u16 smem[2][20480];   // 80 KB

  const int cA = (tid & 3) ^ ((tid >> 3) & 3);
  const u16* srcA[4]; int dstA[4];
#pragma unroll
  for (int q = 0; q < 4; ++q) {
    const int rr = q * 128 + (tid >> 2);
    int g = mt * 512 + rr; if (g >= cnt) g = cnt - 1;
    srcA[q] = x16 + (size_t)(ent[pfx + g] >> 1) * DIM + cA * 8;
    dstA[q] = q * 4096 + tid * 8;
  }
  const int rB = tid >> 3, cB = tid & 7;
  const float* pB1 = w1 + ((size_t)e * HID + nt * 64 + rB) * DIM + cB * 4;
  const float* pB2 = w2 + ((size_t)e * HID + nt * 64 + rB) * DIM + cB * 4;
  const int pos8 = cB ^ (((rB >> 1) & 3) << 1);
  const int wb1 = 16384 + rB * 32 + pos8 * 4;
  const int wb2 = 18432 + rB * 32 + pos8 * 4;

  const int xs = ((l >> 4) ^ ((l >> 1) & 3)) * 8;
  const int ra = (w * 64 + (l & 15)) * 32;
  const int rbb = (l & 15) * 32;

  f32x4 acc1[4][4], acc2[4][4];
#pragma unroll
  for (int m = 0; m < 4; ++m)
#pragma unroll
    for (int n = 0; n < 4; ++n) {
      acc1[m][n] = (f32x4){0.f, 0.f, 0.f, 0.f};
      acc2[m][n] = (f32x4){0.f, 0.f, 0.f, 0.f};
    }

  f32x4 a0_, a1_;
  f32x4 b0_, b1_;

  auto LOADB = [&](f32x4& r0_, f32x4& r1_, int kt) {
    r0_ = *(const f32x4*)(pB1 + kt * 32);
    r1_ = *(const f32x4*)(pB2 + kt * 32);
  };
  auto STAGEA = [&](int buf, int kt) {
#pragma unroll
    for (int q = 0; q < 4; ++q) gld_lds16(srcA[q] + kt * 32, &smem[buf][dstA[q]]);
  };
  auto WRITEB = [&](int buf, const f32x4& r0_, const f32x4& r1_) {
    u16 u[8];
    u[0] = f2b(r0_[0]); u[1] = f2b(r0_[1]); u[2] = f2b(r0_[2]); u[3] = f2b(r0_[3]);
    u[4] = f2b(r1_[0]); u[5] = f2b(r1_[1]); u[6] = f2b(r1_[2]); u[7] = f2b(r1_[3]);
    *(s16x4*)&smem[buf][wb1] = *(const s16x4*)u;
    *(s16x4*)&smem[buf][wb2] = *(const s16x4*)(u + 4);
  };
  auto MSTEP = [&](int buf) {
    const u16* S = &smem[buf][0];
    s16x8 af[4];
#pragma unroll
    for (int m = 0; m < 4; ++m) af[m] = *(const s16x8*)(S + ra + m * 512 + xs);
    __builtin_amdgcn_s_setprio(1);
#pragma unroll
    for (int n = 0; n < 4; ++n) {
      s16x8 bf1 = *(const s16x8*)(S + 16384 + n * 512 + rbb + xs);
      s16x8 bf2 = *(const s16x8*)(S + 18432 + n * 512 + rbb + xs);
#pragma unroll
      for (int m = 0; m < 4; ++m) {
        acc1[m][n] = __builtin_amdgcn_mfma_f32_16x16x32_bf16(af[m], bf1, acc1[m][n], 0, 0, 0);
        acc2[m][n] = __builtin_amdgcn_mfma_f32_16x16x32_bf16(af[m], bf2, acc2[m][n], 0, 0, 0);
      }
    }
    __builtin_amdgcn_s_setprio(0);
  };

  const int NT = DIM / 32;
  LOADB(a0_, a1_, 0);
  STAGEA(0, 0);
  LOADB(b0_, b1_, 1);
  asm volatile("s_waitcnt vmcnt(2)" ::: "memory");
  __builtin_amdgcn_sched_barrier(0);
  WRITEB(0, a0_, a1_);
  STAGEA(1, 1);
  asm volatile("s_waitcnt lgkmcnt(0)" ::: "memory");
  __builtin_amdgcn_sched_barrier(0);
  __builtin_amdgcn_s_barrier();

  for (int kt = 0; kt < NT; kt += 2) {
    if (kt + 2 < NT) LOADB(a0_, a1_, kt + 2);
    MSTEP(0);
    __builtin_amdgcn_s_barrier();
    if (kt + 2 < NT) asm volatile("s_waitcnt vmcnt(2)" ::: "memory");
    else             asm volatile("s_waitcnt vmcnt(0)" ::: "memory");
    __builtin_amdgcn_sched_barrier(0);
    WRITEB(1, b0_, b1_);
    if (kt + 2 < NT) STAGEA(0, kt + 2);
    asm volatile("s_waitcnt lgkmcnt(0)" ::: "memory");
    __builtin_amdgcn_sched_barrier(0);
    __builtin_amdgcn_s_barrier();
    if (kt + 3 < NT) LOADB(b0_, b1_, kt + 3);
    MSTEP(1);
    if (kt + 2 < NT) {
      __builtin_amdgcn_s_barrier();
      if (kt + 3 < NT) asm volatile("s_waitcnt vmcnt(2)" ::: "memory");
      else             asm volatile("s_waitcnt vmcnt(0)" ::: "memory");
      __builtin_amdgcn_sched_barrier(0);
      WRITEB(0, a0_, a1_);
      if (kt + 3 < NT) STAGEA(1, kt + 3);
      asm volatile("s_waitcnt lgkmcnt(0)" ::: "memory");
      __builtin_amdgcn_sched_barrier(0);
      __builtin_amdgcn_s_barrier();
    }
  }

#pragma unroll
  for (int n = 0; n < 4; ++n) {
    const int col = nt * 64 + n * 16 + (l & 15);
    const float bb1 = b1[(size_t)e * HID + col];
    const float bb2 = b2[(size_t)e * HID + col];
#pragma unroll
    for (int m = 0; m < 4; ++m) {
#pragma unroll
      for (int r = 0; r < 4; ++r) {
        const int row = mt * 512 + w * 64 + m * 16 + (l >> 4) * 4 + r;
        if (row < cnt) {
          float h = acc1[m][n][r] + bb1;
          float g = acc2[m][n][r] + bb2;
          float a = h * g / (1.f + expf(-g));
          act[(size_t)(pfx + row) * HID + col] = f2b(a);
        }
      }
    }
  }
}

// ====== GEMM2: 512x128 tile, split-K=4, XCD-pinned ((tile,sk) pair -> XCD p%8) ======
// grid: 512 flat blocks. decode: xcd=b&7, nt=(b>>3)&7, j=b>>6 (0..7), p=xcd+8j.
__global__ __launch_bounds__(512) void k_gemm2f(const u16* __restrict__ act,
    const float* __restrict__ wp, const float* __restrict__ bp,
    const float* __restrict__ entw, const int* __restrict__ counts,
    const int* __restrict__ prefix, const int* __restrict__ tile_tab,
    float* __restrict__ yp) {
  const int bfl = blockIdx.x;
  const int xcd = bfl & 7;
  const int k2 = bfl >> 3;
  const int nt = k2 & 7;          // 0..7
  const int j = k2 >> 3;          // 0..7
  const int p = xcd + 8 * j;      // 0..63
  const int tile = p >> 2, sk = p & 3;   // tile 0..15
  const int tt = tile_tab[tile];
  if (tt < 0) return;
  const int e = tt >> 16, mt = tt & 0xffff;
  const int cnt = counts[e];
  const int pfx = prefix[e];
  const int tid = threadIdx.x, w = tid >> 6, l = tid & 63;

  __shared__ u16 smem[2][20480];

  const int kbase = sk * (HID / KSPLIT);
  const int cA = (tid & 3) ^ ((tid >> 3) & 3);
  const u16* srcA[4]; int dstA[4];
#pragma unroll
  for (int q = 0; q < 4; ++q) {
    const int rr = q * 128 + (tid >> 2);
    int g = mt * 512 + rr; if (g >= cnt) g = cnt - 1;
    srcA[q] = act + (size_t)(pfx + g) * HID + kbase + cA * 8;
    dstA[q] = q * 4096 + tid * 8;
  }
  const int rB = tid >> 2;
  const float* pB = wp + ((size_t)e * DIM + nt * 128 + rB) * HID + kbase + (tid & 3) * 8;
  const int c0 = ((tid & 3) * 2) ^ (((rB >> 1) & 3) << 1);
  const int c1 = ((tid & 3) * 2 + 1) ^ (((rB >> 1) & 3) << 1);
  const int wbB = 16384 + rB * 32;

  const int xs = ((l >> 4) ^ ((l >> 1) & 3)) * 8;
  const int ra = (w * 64 + (l & 15)) * 32;
  const int rbb = (l & 15) * 32;

  f32x4 acc[4][8];
#pragma unroll
  for (int m = 0; m < 4; ++m)
#pragma unroll
    for (int n = 0; n < 8; ++n) acc[m][n] = (f32x4){0.f, 0.f, 0.f, 0.f};

  f32x4 a0_, a1_;
  f32x4 b0_, b1_;

  auto LOADB = [&](f32x4& r0_, f32x4& r1_, int kt) {
    r0_ = *(const f32x4*)(pB + kt * 32);
    r1_ = *(const f32x4*)(pB + kt * 32 + 4);
  };
  auto STAGEA = [&](int buf, int kt) {
#pragma unroll
    for (int q = 0; q < 4; ++q) gld_lds16(srcA[q] + kt * 32, &smem[buf][dstA[q]]);
  };
  auto WRITEB = [&](int buf, const f32x4& r0_, const f32x4& r1_) {
    u16 u[8];
    u[0] = f2b(r0_[0]); u[1] = f2b(r0_[1]); u[2] = f2b(r0_[2]); u[3] = f2b(r0_[3]);
    u[4] = f2b(r1_[0]); u[5] = f2b(r1_[1]); u[6] = f2b(r1_[2]); u[7] = f2b(r1_[3]);
    *(s16x4*)&smem[buf][wbB + c0 * 4] = *(const s16x4*)u;
    *(s16x4*)&smem[buf][wbB + c1 * 4] = *(const s16x4*)(u + 4);
  };
  auto MSTEP = [&](int buf) {
    const u16* S = &smem[buf][0];
    s16x8 af[4];
#pragma unroll
    for (int m = 0; m < 4; ++m) af[m] = *(const s16x8*)(S + ra + m * 512 + xs);
    __builtin_amdgcn_s_setprio(1);
#pragma unroll
    for (int n = 0; n < 8; ++n) {
      s16x8 bf = *(const s16x8*)(S + 16384 + n * 512 + rbb + xs);
#pragma unroll
      for (int m = 0; m < 4; ++m)
        acc[m][n] = __builtin_amdgcn_mfma_f32_16x16x32_bf16(af[m], bf, acc[m][n], 0, 0, 0);
    }
    __builtin_amdgcn_s_setprio(0);
  };

  const int NT = HID / KSPLIT / 32;
  LOADB(a0_, a1_, 0);
  STAGEA(0, 0);
  LOADB(b0_, b1_, 1);
  asm volatile("s_waitcnt vmcnt(2)" ::: "memory");
  __builtin_amdgcn_sched_barrier(0);
  WRITEB(0, a0_, a1_);
  STAGEA(1, 1);
  asm volatile("s_waitcnt lgkmcnt(0)" ::: "memory");
  __builtin_amdgcn_sched_barrier(0);
  __builtin_amdgcn_s_barrier();

  for (int kt = 0; kt < NT; kt += 2) {
    if (kt + 2 < NT) LOADB(a0_, a1_, kt + 2);
    MSTEP(0);
    __builtin_amdgcn_s_barrier();
    if (kt + 2 < NT) asm volatile("s_waitcnt vmcnt(2)" ::: "memory");
    else             asm volatile("s_waitcnt vmcnt(0)" ::: "memory");
    __builtin_amdgcn_sched_barrier(0);
    WRITEB(1, b0_, b1_);
    if (kt + 2 < NT) STAGEA(0, kt + 2);
    asm volatile("s_waitcnt lgkmcnt(0)" ::: "memory");
    __builtin_amdgcn_sched_barrier(0);
    __builtin_amdgcn_s_barrier();
    if (kt + 3 < NT) LOADB(b0_, b1_, kt + 3);
    MSTEP(1);
    if (kt + 2 < NT) {
      __builtin_amdgcn_s_barrier();
      if (kt + 3 < NT) asm volatile("s_waitcnt vmcnt(2)" ::: "memory");
      else             asm volatile("s_waitcnt vmcnt(0)" ::: "memory");
      __builtin_amdgcn_sched_barrier(0);
      WRITEB(0, a0_, a1_);
      if (kt + 3 < NT) STAGEA(1, kt + 3);
      asm volatile("s_waitcnt lgkmcnt(0)" ::: "memory");
      __builtin_amdgcn_sched_barrier(0);
      __builtin_amdgcn_s_barrier();
    }
  }

#pragma unroll
  for (int n = 0; n < 8; ++n) {
    const int col = nt * 128 + n * 16 + (l & 15);
    const float bpv = (sk == 0) ? bp[(size_t)e * DIM + col] : 0.f;
#pragma unroll
    for (int m = 0; m < 4; ++m) {
#pragma unroll
      for (int r = 0; r < 4; ++r) {
        const int row = mt * 512 + w * 64 + m * 16 + (l >> 4) * 4 + r;
        if (row < cnt) {
          const int idx = pfx + row;
          yp[((size_t)sk * (TOK * 2) + idx) * DIM + col] = entw[idx] * (acc[m][n][r] + bpv);
        }
      }
    }
  }
}

// ---------------- final: out[t] = sum over 2 slots x KSPLIT partials ----------------
__global__ __launch_bounds__(256) void k_final(const float* __restrict__ yp,
    const int* __restrict__ inv, float* __restrict__ out) {
  const int t = blockIdx.x;
  const int d = threadIdx.x * 4;
  const int i0 = inv[t * 2], i1 = inv[t * 2 + 1];
  float4 s = {0.f, 0.f, 0.f, 0.f};
#pragma unroll
  for (int sk = 0; sk < KSPLIT; ++sk) {
    float4 a = *(const float4*)(yp + ((size_t)sk * (TOK * 2) + i0) * DIM + d);
    float4 b = *(const float4*)(yp + ((size_t)sk * (TOK * 2) + i1) * DIM + d);
    s.x += a.x + b.x; s.y += a.y + b.y; s.z += a.z + b.z; s.w += a.w + b.w;
  }
  *(float4*)(out + (size_t)t * DIM + d) = s;
}

extern "C" void kernel_launch(void* const* d_in, const int* in_sizes, int n_in,
                              void* d_out, int out_size, void* d_ws, size_t ws_size,
                              hipStream_t stream) {
  const float* x      = (const float*)d_in[0];
  const float* noise  = (const float*)d_in[1];
  const float* gate_w = (const float*)d_in[2];
  const float* nw     = (const float*)d_in[3];
  const float* w1     = (const float*)d_in[4];
  const float* b1     = (const float*)d_in[5];
  const float* w2     = (const float*)d_in[6];
  const float* b2     = (const float*)d_in[7];
  const float* wp     = (const float*)d_in[8];
  const float* bp     = (const float*)d_in[9];
  float* out = (float*)d_out;
  char* ws = (char*)d_ws;

  const size_t SZ_X16 = (size_t)TOK * DIM * 2;
  const size_t SZ_ACT = (size_t)TOK * 2 * HID * 2;
  const size_t SZ_YP  = (size_t)KSPLIT * TOK * 2 * DIM * 4;

  u16* x16  = (u16*)ws;
  u16* act  = (u16*)(ws + SZ_X16);
  float* yp = (float*)(ws + SZ_X16 + SZ_ACT);
  char* meta = ws + SZ_X16 + SZ_ACT + SZ_YP;
  int*   tok_e    = (int*)(meta);
  float* tok_w    = (float*)(meta + 16384);
  int*   ent      = (int*)(meta + 32768);
  float* entw     = (float*)(meta + 49152);
  int*   bhist    = (int*)(meta + 65536);
  float* bgw      = (float*)(meta + 81920);
  int*   blk_off  = (int*)(meta + 98304);
  int*   inv      = (int*)(meta + 114688);
  int*   counts   = (int*)(meta + 131072);
  int*   prefix   = (int*)(meta + 131072 + 64);
  int*   tile_tab = (int*)(meta + 131072 + 128);

  k_gate<<<TOK / 4, 256, 0, stream>>>(x, noise, gate_w, nw, tok_e, tok_w, bhist, bgw, x16);
  k_scan<<<1, 512, 0, stream>>>(bhist, bgw, blk_off, prefix, counts, tile_tab,
                                out + (size_t)TOK * DIM);
  k_build<<<TOK / 256, 256, 0, stream>>>(tok_e, tok_w, prefix, blk_off, ent, entw, inv);
  k_gemm1f<<<1024, 512, 0, stream>>>(x16, w1, w2, b1, b2, ent,
                                     counts, prefix, tile_tab, act);
  k_gemm2f<<<512, 512, 0, stream>>>(act, wp, bp, entw,
                                    counts, prefix, tile_tab, yp);
  k_final<<<TOK, 256, 0, stream>>>(yp, inv, out);
}

// Round 17
// 350.195 us; speedup vs baseline: 1.0683x; 1.0683x over previous
//
#include <hip/hip_runtime.h>

#define TOK 2048
#define DIM 1024
#define HID 4096
#define NE 8
#define KSPLIT 4
#define T2MAX 16

typedef unsigned short u16;
typedef __attribute__((ext_vector_type(8))) short s16x8;
typedef __attribute__((ext_vector_type(4))) short s16x4;
typedef __attribute__((ext_vector_type(4))) float f32x4;

__device__ __forceinline__ u16 f2b(float f) {
  unsigned u = __builtin_bit_cast(unsigned, f);
  unsigned r = (u + 0x7fffu + ((u >> 16) & 1u)) >> 16;
  return (u16)r;
}

__device__ __forceinline__ void gld_lds16(const void* g, void* l) {
  __builtin_amdgcn_global_load_lds((const __attribute__((address_space(1))) void*)g,
                                   (__attribute__((address_space(3))) void*)l, 16, 0, 0);
}

// ---------------- gating: one wave per token (512 blocks) ----------------
__global__ __launch_bounds__(256) void k_gate(const float* __restrict__ x,
    const float* __restrict__ noise, const float* __restrict__ gw,
    const float* __restrict__ nw,
    int* __restrict__ tok_e, float* __restrict__ tok_w,
    int* __restrict__ bhist, float* __restrict__ bgw, u16* __restrict__ x16) {
  const int wid = threadIdx.x >> 6, lane = threadIdx.x & 63;
  const int t = blockIdx.x * 4 + wid;
  const float* xr = x + (size_t)t * DIM + lane * 16;
  float acc[NE];
#pragma unroll
  for (int e = 0; e < NE; ++e) acc[e] = 0.f;
  u16 xb[16];
#pragma unroll
  for (int j = 0; j < 4; ++j) {
    float4 xv = *(const float4*)(xr + j * 4);
    xb[j * 4 + 0] = f2b(xv.x); xb[j * 4 + 1] = f2b(xv.y);
    xb[j * 4 + 2] = f2b(xv.z); xb[j * 4 + 3] = f2b(xv.w);
#pragma unroll
    for (int e = 0; e < NE; ++e) {
      float4 gv = *(const float4*)(gw + e * DIM + lane * 16 + j * 4);
      acc[e] += xv.x * gv.x + xv.y * gv.y + xv.z * gv.z + xv.w * gv.w;
    }
  }
  *(s16x8*)(x16 + (size_t)t * DIM + lane * 16) = *(const s16x8*)xb;
  *(s16x8*)(x16 + (size_t)t * DIM + lane * 16 + 8) = *(const s16x8*)(xb + 8);
#pragma unroll
  for (int e = 0; e < NE; ++e) {
#pragma unroll
    for (int off = 32; off >= 1; off >>= 1) acc[e] += __shfl_xor(acc[e], off);
  }
  float m = acc[0];
#pragma unroll
  for (int e = 1; e < NE; ++e) m = fmaxf(m, acc[e]);
  float p[NE]; float s = 0.f;
#pragma unroll
  for (int e = 0; e < NE; ++e) { p[e] = expf(acc[e] - m); s += p[e]; }
  float inv = 1.f / s;
  float v[NE];
#pragma unroll
  for (int e = 0; e < NE; ++e) v[e] = acc[e] + noise[t * NE + e] * nw[e];
  float v0 = -3.4e38f, v1 = -3.4e38f; int i0 = 0, i1 = 0;
#pragma unroll
  for (int e = 0; e < NE; ++e) {
    float ve = v[e];
    if (ve > v0) { v1 = v0; i1 = i0; v0 = ve; i0 = e; }
    else if (ve > v1) { v1 = ve; i1 = e; }
  }
  float e1 = expf(v1 - v0);
  float den = 1.f + e1;
  float w0 = 1.f / den, w1v = e1 / den;

  __shared__ float pl[4][NE];
  __shared__ int el[4][2];
  if (lane == 0) {
#pragma unroll
    for (int e = 0; e < NE; ++e) pl[wid][e] = p[e] * inv;
    el[wid][0] = i0; el[wid][1] = i1;
    tok_e[t * 2] = i0; tok_e[t * 2 + 1] = i1;
    tok_w[t * 2] = w0; tok_w[t * 2 + 1] = w1v;
  }
  __syncthreads();
  if (threadIdx.x < NE) {
    const int e = threadIdx.x;
    float ps = pl[0][e] + pl[1][e] + pl[2][e] + pl[3][e];
    int h = 0;
#pragma unroll
    for (int j = 0; j < 4; ++j) {
      h += (el[j][0] == e);
      h += (el[j][1] == e);
    }
    bgw[blockIdx.x * NE + e] = ps;
    bhist[blockIdx.x * NE + e] = h;
  }
}

// ---------------- scan: offsets, counts, prefix, 512-row tile table, lb loss ----------------
__global__ __launch_bounds__(512) void k_scan(const int* __restrict__ bhist,
    const float* __restrict__ bgw, int* __restrict__ blk_off, int* __restrict__ prefix,
    int* __restrict__ counts, int* __restrict__ tile_tab, float* __restrict__ loss_out) {
  const int i = threadIdx.x, lane = i & 63, wv = i >> 6;
  __shared__ int wsum[8];
  __shared__ float wfs[8];
  __shared__ int etot[8];
  __shared__ float fsum[8];
  for (int e = 0; e < NE; ++e) {
    int v = bhist[i * NE + e];
    int sc = v;
#pragma unroll
    for (int off = 1; off < 64; off <<= 1) {
      int u = __shfl_up(sc, off);
      if (lane >= off) sc += u;
    }
    float f = bgw[i * NE + e];
#pragma unroll
    for (int off = 32; off >= 1; off >>= 1) f += __shfl_xor(f, off);
    if (lane == 63) wsum[wv] = sc;
    if (lane == 0) wfs[wv] = f;
    __syncthreads();
    int base = 0;
    for (int w2 = 0; w2 < wv; ++w2) base += wsum[w2];
    blk_off[i * NE + e] = base + sc - v;
    if (i == 0) {
      float tf = 0.f;
      for (int w2 = 0; w2 < 8; ++w2) tf += wfs[w2];
      fsum[e] = tf;
    }
    if (i == 511) etot[e] = base + sc;
    __syncthreads();
  }
  if (i == 0) {
    int sacc = 0;
    float l = 0.f;
    int tt = 0;
#pragma unroll
    for (int e = 0; e < NE; ++e) { prefix[e] = sacc; counts[e] = etot[e]; sacc += etot[e]; }
    for (int e = 0; e < NE; ++e) {
      const int nmt = (etot[e] + 511) >> 9;
      for (int m2 = 0; m2 < nmt && tt < T2MAX; ++m2) tile_tab[tt++] = (e << 16) | m2;
    }
    for (; tt < T2MAX; ++tt) tile_tab[tt] = -1;
#pragma unroll
    for (int e = 0; e < NE; ++e) {
      float d = fsum[e] * (1.f / TOK) - 0.125f;
      l += d * d;
    }
    *loss_out = l * (0.01f / NE);
  }
}

// ---------------- build compacted expert lists + inverse map ----------------
__global__ __launch_bounds__(256) void k_build(const int* __restrict__ tok_e,
    const float* __restrict__ tok_w, const int* __restrict__ prefix,
    const int* __restrict__ blk_off, int* __restrict__ ent, float* __restrict__ entw,
    int* __restrict__ inv) {
  const int t = blockIdx.x * 256 + threadIdx.x;
  const int g = t >> 2;
  const int base = (t & 3) * 2;
  int ee[8];
#pragma unroll
  for (int j = 0; j < 8; ++j) ee[j] = tok_e[g * 8 + j];
#pragma unroll
  for (int s = 0; s < 2; ++s) {
    const int e = ee[base + s];
    int rank = 0;
#pragma unroll
    for (int j = 0; j < 8; ++j) rank += (j < base + s) && (ee[j] == e);
    const int idx = prefix[e] + blk_off[g * NE + e] + rank;
    ent[idx] = t * 2 + s;
    entw[idx] = tok_w[t * 2 + s];
    inv[t * 2 + s] = idx;
  }
}

// ====== GEMM1: 512x64 tile, weights once, TRIPLE-buffer 1-barrier/step pipeline ======
// LDS (u16 idx): A bufs 0/16384/32768 (512x32 each); B bufs 49152+j*4096 (B1 2048 + B2 2048)
__global__ __launch_bounds__(512) void k_gemm1f(const u16* __restrict__ x16,
    const float* __restrict__ w1, const float* __restrict__ w2,
    const float* __restrict__ b1, const float* __restrict__ b2,
    const int* __restrict__ ent, const int* __restrict__ counts,
    const int* __restrict__ prefix, const int* __restrict__ tile_tab,
    u16* __restrict__ act) {
  const int tt = tile_tab[blockIdx.y];
  if (tt < 0) return;
  const int e = tt >> 16, mt = tt & 0xffff, nt = blockIdx.x;   // nt 0..63
  const int cnt = counts[e];
  const int pfx = prefix[e];
  const int tid = threadIdx.x, w = tid >> 6, l = tid & 63;

  __shared__ u16 smem[61440];   // 120 KB

  const int cA = (tid & 3) ^ ((tid >> 3) & 3);
  const u16* srcA[4];
#pragma unroll
  for (int q = 0; q < 4; ++q) {
    const int rr = q * 128 + (tid >> 2);
    int g = mt * 512 + rr; if (g >= cnt) g = cnt - 1;
    srcA[q] = x16 + (size_t)(ent[pfx + g] >> 1) * DIM + cA * 8;
  }
  const int rB = tid >> 3, cB = tid & 7;
  const float* pB1 = w1 + ((size_t)e * HID + nt * 64 + rB) * DIM + cB * 4;
  const float* pB2 = w2 + ((size_t)e * HID + nt * 64 + rB) * DIM + cB * 4;
  const int pos8 = cB ^ (((rB >> 1) & 3) << 1);
  const int wbOff = rB * 32 + pos8 * 4;

  const int xs = ((l >> 4) ^ ((l >> 1) & 3)) * 8;
  const int ra = (w * 64 + (l & 15)) * 32;
  const int rbb = (l & 15) * 32;

  f32x4 acc1[4][4], acc2[4][4];
#pragma unroll
  for (int m = 0; m < 4; ++m)
#pragma unroll
    for (int n = 0; n < 4; ++n) {
      acc1[m][n] = (f32x4){0.f, 0.f, 0.f, 0.f};
      acc2[m][n] = (f32x4){0.f, 0.f, 0.f, 0.f};
    }

  f32x4 rA0, rA1;   // even-step load set
  f32x4 rB0, rB1;   // odd-step load set

#define LB1(R0, R1, KT) { R0 = *(const f32x4*)(pB1 + (KT) * 32); R1 = *(const f32x4*)(pB2 + (KT) * 32); }
#define ST1(NXT, KT) { _Pragma("unroll") for (int q = 0; q < 4; ++q) \
    gld_lds16(srcA[q] + (KT) * 32, &smem[(NXT) * 16384 + q * 4096 + tid * 8]); }
#define WB1(WBUF, R0, R1) { u16 u_[8]; \
    u_[0] = f2b(R0[0]); u_[1] = f2b(R0[1]); u_[2] = f2b(R0[2]); u_[3] = f2b(R0[3]); \
    u_[4] = f2b(R1[0]); u_[5] = f2b(R1[1]); u_[6] = f2b(R1[2]); u_[7] = f2b(R1[3]); \
    *(s16x4*)&smem[49152 + (WBUF) * 4096 + wbOff] = *(const s16x4*)u_; \
    *(s16x4*)&smem[49152 + (WBUF) * 4096 + 2048 + wbOff] = *(const s16x4*)(u_ + 4); }
#define MS1(CUR) { s16x8 af_[4]; \
    _Pragma("unroll") for (int m = 0; m < 4; ++m) \
      af_[m] = *(const s16x8*)&smem[(CUR) * 16384 + ra + m * 512 + xs]; \
    __builtin_amdgcn_s_setprio(1); \
    _Pragma("unroll") for (int n = 0; n < 4; ++n) { \
      s16x8 bf1_ = *(const s16x8*)&smem[49152 + (CUR) * 4096 + n * 512 + rbb + xs]; \
      s16x8 bf2_ = *(const s16x8*)&smem[49152 + (CUR) * 4096 + 2048 + n * 512 + rbb + xs]; \
      _Pragma("unroll") for (int m = 0; m < 4; ++m) { \
        acc1[m][n] = __builtin_amdgcn_mfma_f32_16x16x32_bf16(af_[m], bf1_, acc1[m][n], 0, 0, 0); \
        acc2[m][n] = __builtin_amdgcn_mfma_f32_16x16x32_bf16(af_[m], bf2_, acc2[m][n], 0, 0, 0); \
      } \
    } \
    __builtin_amdgcn_s_setprio(0); }
#define STEP1(S_, CUR, WB, NXT, RL0, RL1, RW0, RW1) \
    LB1(RL0, RL1, (S_) + 2); \
    asm volatile("s_waitcnt vmcnt(6)" ::: "memory"); \
    __builtin_amdgcn_sched_barrier(0); \
    WB1(WB, RW0, RW1); \
    ST1(NXT, (S_) + 2); \
    MS1(CUR); \
    asm volatile("s_waitcnt lgkmcnt(0)" ::: "memory"); \
    asm volatile("s_waitcnt vmcnt(6)" ::: "memory"); \
    __builtin_amdgcn_sched_barrier(0); \
    __builtin_amdgcn_s_barrier();

  const int NT = DIM / 32;   // 32
  // prologue: tile0 complete in bufs 0, tile1 staged (A buf1, rgB), tile1 B written at step0
  LB1(rA0, rA1, 0);
  ST1(0, 0);
  LB1(rB0, rB1, 1);
  ST1(1, 1);
  asm volatile("s_waitcnt vmcnt(10)" ::: "memory");
  __builtin_amdgcn_sched_barrier(0);
  WB1(0, rA0, rA1);
  asm volatile("s_waitcnt vmcnt(6)" ::: "memory");
  asm volatile("s_waitcnt lgkmcnt(0)" ::: "memory");
  __builtin_amdgcn_sched_barrier(0);
  __builtin_amdgcn_s_barrier();

  for (int kt = 0; kt < NT - 2; kt += 6) {
    STEP1(kt + 0, 0, 1, 2, rA0, rA1, rB0, rB1);
    STEP1(kt + 1, 1, 2, 0, rB0, rB1, rA0, rA1);
    STEP1(kt + 2, 2, 0, 1, rA0, rA1, rB0, rB1);
    STEP1(kt + 3, 0, 1, 2, rB0, rB1, rA0, rA1);
    STEP1(kt + 4, 1, 2, 0, rA0, rA1, rB0, rB1);
    STEP1(kt + 5, 2, 0, 1, rB0, rB1, rA0, rA1);
  }
  // step NT-2 (=30): CUR 0, write tile31 (set odd) into B buf1
  asm volatile("s_waitcnt vmcnt(4)" ::: "memory");
  __builtin_amdgcn_sched_barrier(0);
  WB1(1, rB0, rB1);
  MS1(0);
  asm volatile("s_waitcnt lgkmcnt(0)" ::: "memory");
  asm volatile("s_waitcnt vmcnt(0)" ::: "memory");
  __builtin_amdgcn_sched_barrier(0);
  __builtin_amdgcn_s_barrier();
  // step NT-1 (=31):
  MS1(1);

#undef LB1
#undef ST1
#undef WB1
#undef MS1
#undef STEP1

#pragma unroll
  for (int n = 0; n < 4; ++n) {
    const int col = nt * 64 + n * 16 + (l & 15);
    const float bb1 = b1[(size_t)e * HID + col];
    const float bb2 = b2[(size_t)e * HID + col];
#pragma unroll
    for (int m = 0; m < 4; ++m) {
#pragma unroll
      for (int r = 0; r < 4; ++r) {
        const int row = mt * 512 + w * 64 + m * 16 + (l >> 4) * 4 + r;
        if (row < cnt) {
          float h = acc1[m][n][r] + bb1;
          float g = acc2[m][n][r] + bb2;
          float a = h * g / (1.f + expf(-g));
          act[(size_t)(pfx + row) * HID + col] = f2b(a);
        }
      }
    }
  }
}

// ====== GEMM2: 512x128 tile, split-K=4, wp once, TRIPLE-buffer 1-barrier/step ======
// LDS (u16 idx): A bufs 0/16384/32768 (512x32); B bufs 49152+j*4096 (128x32)
__global__ __launch_bounds__(512) void k_gemm2f(const u16* __restrict__ act,
    const float* __restrict__ wp, const float* __restrict__ bp,
    const float* __restrict__ entw, const int* __restrict__ counts,
    const int* __restrict__ prefix, const int* __restrict__ tile_tab,
    float* __restrict__ yp) {
  const int tt = tile_tab[blockIdx.y];
  if (tt < 0) return;
  const int e = tt >> 16, mt = tt & 0xffff;
  const int sk = blockIdx.z, nt = blockIdx.x;   // nt 0..7
  const int cnt = counts[e];
  const int pfx = prefix[e];
  const int tid = threadIdx.x, w = tid >> 6, l = tid & 63;

  __shared__ u16 smem[61440];

  const int kbase = sk * (HID / KSPLIT);
  const int cA = (tid & 3) ^ ((tid >> 3) & 3);
  const u16* srcA[4];
#pragma unroll
  for (int q = 0; q < 4; ++q) {
    const int rr = q * 128 + (tid >> 2);
    int g = mt * 512 + rr; if (g >= cnt) g = cnt - 1;
    srcA[q] = act + (size_t)(pfx + g) * HID + kbase + cA * 8;
  }
  const int rB = tid >> 2;
  const float* pB = wp + ((size_t)e * DIM + nt * 128 + rB) * HID + kbase + (tid & 3) * 8;
  const int c0 = ((tid & 3) * 2) ^ (((rB >> 1) & 3) << 1);
  const int c1 = ((tid & 3) * 2 + 1) ^ (((rB >> 1) & 3) << 1);
  const int wbOff = rB * 32;

  const int xs = ((l >> 4) ^ ((l >> 1) & 3)) * 8;
  const int ra = (w * 64 + (l & 15)) * 32;
  const int rbb = (l & 15) * 32;

  f32x4 acc[4][8];
#pragma unroll
  for (int m = 0; m < 4; ++m)
#pragma unroll
    for (int n = 0; n < 8; ++n) acc[m][n] = (f32x4){0.f, 0.f, 0.f, 0.f};

  f32x4 rA0, rA1;
  f32x4 rB0, rB1;

#define LB2(R0, R1, KT) { R0 = *(const f32x4*)(pB + (KT) * 32); R1 = *(const f32x4*)(pB + (KT) * 32 + 4); }
#define ST2(NXT, KT) { _Pragma("unroll") for (int q = 0; q < 4; ++q) \
    gld_lds16(srcA[q] + (KT) * 32, &smem[(NXT) * 16384 + q * 4096 + tid * 8]); }
#define WB2(WBUF, R0, R1) { u16 u_[8]; \
    u_[0] = f2b(R0[0]); u_[1] = f2b(R0[1]); u_[2] = f2b(R0[2]); u_[3] = f2b(R0[3]); \
    u_[4] = f2b(R1[0]); u_[5] = f2b(R1[1]); u_[6] = f2b(R1[2]); u_[7] = f2b(R1[3]); \
    *(s16x4*)&smem[49152 + (WBUF) * 4096 + wbOff + c0 * 4] = *(const s16x4*)u_; \
    *(s16x4*)&smem[49152 + (WBUF) * 4096 + wbOff + c1 * 4] = *(const s16x4*)(u_ + 4); }
#define MS2(CUR) { s16x8 af_[4]; \
    _Pragma("unroll") for (int m = 0; m < 4; ++m) \
      af_[m] = *(const s16x8*)&smem[(CUR) * 16384 + ra + m * 512 + xs]; \
    __builtin_amdgcn_s_setprio(1); \
    _Pragma("unroll") for (int n = 0; n < 8; ++n) { \
      s16x8 bf_ = *(const s16x8*)&smem[49152 + (CUR) * 4096 + n * 512 + rbb + xs]; \
      _Pragma("unroll") for (int m = 0; m < 4; ++m) \
        acc[m][n] = __builtin_amdgcn_mfma_f32_16x16x32_bf16(af_[m], bf_, acc[m][n], 0, 0, 0); \
    } \
    __builtin_amdgcn_s_setprio(0); }
#define STEP2(S_, CUR, WB, NXT, RL0, RL1, RW0, RW1) \
    LB2(RL0, RL1, (S_) + 2); \
    asm volatile("s_waitcnt vmcnt(6)" ::: "memory"); \
    __builtin_amdgcn_sched_barrier(0); \
    WB2(WB, RW0, RW1); \
    ST2(NXT, (S_) + 2); \
    MS2(CUR); \
    asm volatile("s_waitcnt lgkmcnt(0)" ::: "memory"); \
    asm volatile("s_waitcnt vmcnt(6)" ::: "memory"); \
    __builtin_amdgcn_sched_barrier(0); \
    __builtin_amdgcn_s_barrier();

  const int NT = HID / KSPLIT / 32;   // 32
  LB2(rA0, rA1, 0);
  ST2(0, 0);
  LB2(rB0, rB1, 1);
  ST2(1, 1);
  asm volatile("s_waitcnt vmcnt(10)" ::: "memory");
  __builtin_amdgcn_sched_barrier(0);
  WB2(0, rA0, rA1);
  asm volatile("s_waitcnt vmcnt(6)" ::: "memory");
  asm volatile("s_waitcnt lgkmcnt(0)" ::: "memory");
  __builtin_amdgcn_sched_barrier(0);
  __builtin_amdgcn_s_barrier();

  for (int kt = 0; kt < NT - 2; kt += 6) {
    STEP2(kt + 0, 0, 1, 2, rA0, rA1, rB0, rB1);
    STEP2(kt + 1, 1, 2, 0, rB0, rB1, rA0, rA1);
    STEP2(kt + 2, 2, 0, 1, rA0, rA1, rB0, rB1);
    STEP2(kt + 3, 0, 1, 2, rB0, rB1, rA0, rA1);
    STEP2(kt + 4, 1, 2, 0, rA0, rA1, rB0, rB1);
    STEP2(kt + 5, 2, 0, 1, rB0, rB1, rA0, rA1);
  }
  asm volatile("s_waitcnt vmcnt(4)" ::: "memory");
  __builtin_amdgcn_sched_barrier(0);
  WB2(1, rB0, rB1);
  MS2(0);
  asm volatile("s_waitcnt lgkmcnt(0)" ::: "memory");
  asm volatile("s_waitcnt vmcnt(0)" ::: "memory");
  __builtin_amdgcn_sched_barrier(0);
  __builtin_amdgcn_s_barrier();
  MS2(1);

#undef LB2
#undef ST2
#undef WB2
#undef MS2
#undef STEP2

#pragma unroll
  for (int n = 0; n < 8; ++n) {
    const int col = nt * 128 + n * 16 + (l & 15);
    const float bpv = (sk == 0) ? bp[(size_t)e * DIM + col] : 0.f;
#pragma unroll
    for (int m = 0; m < 4; ++m) {
#pragma unroll
      for (int r = 0; r < 4; ++r) {
        const int row = mt * 512 + w * 64 + m * 16 + (l >> 4) * 4 + r;
        if (row < cnt) {
          const int idx = pfx + row;
          yp[((size_t)sk * (TOK * 2) + idx) * DIM + col] = entw[idx] * (acc[m][n][r] + bpv);
        }
      }
    }
  }
}

// ---------------- final: out[t] = sum over 2 slots x KSPLIT partials ----------------
__global__ __launch_bounds__(256) void k_final(const float* __restrict__ yp,
    const int* __restrict__ inv, float* __restrict__ out) {
  const int t = blockIdx.x;
  const int d = threadIdx.x * 4;
  const int i0 = inv[t * 2], i1 = inv[t * 2 + 1];
  float4 s = {0.f, 0.f, 0.f, 0.f};
#pragma unroll
  for (int sk = 0; sk < KSPLIT; ++sk) {
    float4 a = *(const float4*)(yp + ((size_t)sk * (TOK * 2) + i0) * DIM + d);
    float4 b = *(const float4*)(yp + ((size_t)sk * (TOK * 2) + i1) * DIM + d);
    s.x += a.x + b.x; s.y += a.y + b.y; s.z += a.z + b.z; s.w += a.w + b.w;
  }
  *(float4*)(out + (size_t)t * DIM + d) = s;
}

extern "C" void kernel_launch(void* const* d_in, const int* in_sizes, int n_in,
                              void* d_out, int out_size, void* d_ws, size_t ws_size,
                              hipStream_t stream) {
  const float* x      = (const float*)d_in[0];
  const float* noise  = (const float*)d_in[1];
  const float* gate_w = (const float*)d_in[2];
  const float* nw     = (const float*)d_in[3];
  const float* w1     = (const float*)d_in[4];
  const float* b1     = (const float*)d_in[5];
  const float* w2     = (const float*)d_in[6];
  const float* b2     = (const float*)d_in[7];
  const float* wp     = (const float*)d_in[8];
  const float* bp     = (const float*)d_in[9];
  float* out = (float*)d_out;
  char* ws = (char*)d_ws;

  const size_t SZ_X16 = (size_t)TOK * DIM * 2;
  const size_t SZ_ACT = (size_t)TOK * 2 * HID * 2;
  const size_t SZ_YP  = (size_t)KSPLIT * TOK * 2 * DIM * 4;

  u16* x16  = (u16*)ws;
  u16* act  = (u16*)(ws + SZ_X16);
  float* yp = (float*)(ws + SZ_X16 + SZ_ACT);
  char* meta = ws + SZ_X16 + SZ_ACT + SZ_YP;
  int*   tok_e    = (int*)(meta);
  float* tok_w    = (float*)(meta + 16384);
  int*   ent      = (int*)(meta + 32768);
  float* entw     = (float*)(meta + 49152);
  int*   bhist    = (int*)(meta + 65536);
  float* bgw      = (float*)(meta + 81920);
  int*   blk_off  = (int*)(meta + 98304);
  int*   inv      = (int*)(meta + 114688);
  int*   counts   = (int*)(meta + 131072);
  int*   prefix   = (int*)(meta + 131072 + 64);
  int*   tile_tab = (int*)(meta + 131072 + 128);

  k_gate<<<TOK / 4, 256, 0, stream>>>(x, noise, gate_w, nw, tok_e, tok_w, bhist, bgw, x16);
  k_scan<<<1, 512, 0, stream>>>(bhist, bgw, blk_off, prefix, counts, tile_tab,
                                out + (size_t)TOK * DIM);
  k_build<<<TOK / 256, 256, 0, stream>>>(tok_e, tok_w, prefix, blk_off, ent, entw, inv);
  k_gemm1f<<<dim3(HID / 64, T2MAX), 512, 0, stream>>>(x16, w1, w2, b1, b2, ent,
                                                      counts, prefix, tile_tab, act);
  k_gemm2f<<<dim3(DIM / 128, T2MAX, KSPLIT), 512, 0, stream>>>(act, wp, bp, entw,
                                                               counts, prefix, tile_tab, yp);
  k_final<<<TOK, 256, 0, stream>>>(yp, inv, out);
}

// Round 18
// 320.922 us; speedup vs baseline: 1.1658x; 1.0912x over previous
//
#include <hip/hip_runtime.h>

#define TOK 2048
#define DIM 1024
#define HID 4096
#define NE 8
#define KSPLIT 4
#define T2MAX 16

typedef unsigned short u16;
typedef __attribute__((ext_vector_type(8))) short s16x8;
typedef __attribute__((ext_vector_type(4))) short s16x4;
typedef __attribute__((ext_vector_type(4))) float f32x4;

__device__ __forceinline__ u16 f2b(float f) {
  unsigned u = __builtin_bit_cast(unsigned, f);
  unsigned r = (u + 0x7fffu + ((u >> 16) & 1u)) >> 16;
  return (u16)r;
}

__device__ __forceinline__ void gld_lds16(const void* g, void* l) {
  __builtin_amdgcn_global_load_lds((const __attribute__((address_space(1))) void*)g,
                                   (__attribute__((address_space(3))) void*)l, 16, 0, 0);
}

// ---------------- gating: one wave per token (512 blocks) ----------------
__global__ __launch_bounds__(256) void k_gate(const float* __restrict__ x,
    const float* __restrict__ noise, const float* __restrict__ gw,
    const float* __restrict__ nw,
    int* __restrict__ tok_e, float* __restrict__ tok_w,
    int* __restrict__ bhist, float* __restrict__ bgw, u16* __restrict__ x16) {
  const int wid = threadIdx.x >> 6, lane = threadIdx.x & 63;
  const int t = blockIdx.x * 4 + wid;
  const float* xr = x + (size_t)t * DIM + lane * 16;
  float acc[NE];
#pragma unroll
  for (int e = 0; e < NE; ++e) acc[e] = 0.f;
  u16 xb[16];
#pragma unroll
  for (int j = 0; j < 4; ++j) {
    float4 xv = *(const float4*)(xr + j * 4);
    xb[j * 4 + 0] = f2b(xv.x); xb[j * 4 + 1] = f2b(xv.y);
    xb[j * 4 + 2] = f2b(xv.z); xb[j * 4 + 3] = f2b(xv.w);
#pragma unroll
    for (int e = 0; e < NE; ++e) {
      float4 gv = *(const float4*)(gw + e * DIM + lane * 16 + j * 4);
      acc[e] += xv.x * gv.x + xv.y * gv.y + xv.z * gv.z + xv.w * gv.w;
    }
  }
  *(s16x8*)(x16 + (size_t)t * DIM + lane * 16) = *(const s16x8*)xb;
  *(s16x8*)(x16 + (size_t)t * DIM + lane * 16 + 8) = *(const s16x8*)(xb + 8);
#pragma unroll
  for (int e = 0; e < NE; ++e) {
#pragma unroll
    for (int off = 32; off >= 1; off >>= 1) acc[e] += __shfl_xor(acc[e], off);
  }
  float m = acc[0];
#pragma unroll
  for (int e = 1; e < NE; ++e) m = fmaxf(m, acc[e]);
  float p[NE]; float s = 0.f;
#pragma unroll
  for (int e = 0; e < NE; ++e) { p[e] = expf(acc[e] - m); s += p[e]; }
  float inv = 1.f / s;
  float v[NE];
#pragma unroll
  for (int e = 0; e < NE; ++e) v[e] = acc[e] + noise[t * NE + e] * nw[e];
  float v0 = -3.4e38f, v1 = -3.4e38f; int i0 = 0, i1 = 0;
#pragma unroll
  for (int e = 0; e < NE; ++e) {
    float ve = v[e];
    if (ve > v0) { v1 = v0; i1 = i0; v0 = ve; i0 = e; }
    else if (ve > v1) { v1 = ve; i1 = e; }
  }
  float e1 = expf(v1 - v0);
  float den = 1.f + e1;
  float w0 = 1.f / den, w1v = e1 / den;

  __shared__ float pl[4][NE];
  __shared__ int el[4][2];
  if (lane == 0) {
#pragma unroll
    for (int e = 0; e < NE; ++e) pl[wid][e] = p[e] * inv;
    el[wid][0] = i0; el[wid][1] = i1;
    tok_e[t * 2] = i0; tok_e[t * 2 + 1] = i1;
    tok_w[t * 2] = w0; tok_w[t * 2 + 1] = w1v;
  }
  __syncthreads();
  if (threadIdx.x < NE) {
    const int e = threadIdx.x;
    float ps = pl[0][e] + pl[1][e] + pl[2][e] + pl[3][e];
    int h = 0;
#pragma unroll
    for (int j = 0; j < 4; ++j) {
      h += (el[j][0] == e);
      h += (el[j][1] == e);
    }
    bgw[blockIdx.x * NE + e] = ps;
    bhist[blockIdx.x * NE + e] = h;
  }
}

// ---------------- scan: offsets, counts, prefix, 512-row tile table, lb loss ----------------
__global__ __launch_bounds__(512) void k_scan(const int* __restrict__ bhist,
    const float* __restrict__ bgw, int* __restrict__ blk_off, int* __restrict__ prefix,
    int* __restrict__ counts, int* __restrict__ tile_tab, float* __restrict__ loss_out) {
  const int i = threadIdx.x, lane = i & 63, wv = i >> 6;
  __shared__ int wsum[8];
  __shared__ float wfs[8];
  __shared__ int etot[8];
  __shared__ float fsum[8];
  for (int e = 0; e < NE; ++e) {
    int v = bhist[i * NE + e];
    int sc = v;
#pragma unroll
    for (int off = 1; off < 64; off <<= 1) {
      int u = __shfl_up(sc, off);
      if (lane >= off) sc += u;
    }
    float f = bgw[i * NE + e];
#pragma unroll
    for (int off = 32; off >= 1; off >>= 1) f += __shfl_xor(f, off);
    if (lane == 63) wsum[wv] = sc;
    if (lane == 0) wfs[wv] = f;
    __syncthreads();
    int base = 0;
    for (int w2 = 0; w2 < wv; ++w2) base += wsum[w2];
    blk_off[i * NE + e] = base + sc - v;
    if (i == 0) {
      float tf = 0.f;
      for (int w2 = 0; w2 < 8; ++w2) tf += wfs[w2];
      fsum[e] = tf;
    }
    if (i == 511) etot[e] = base + sc;
    __syncthreads();
  }
  if (i == 0) {
    int sacc = 0;
    float l = 0.f;
    int tt = 0;
#pragma unroll
    for (int e = 0; e < NE; ++e) { prefix[e] = sacc; counts[e] = etot[e]; sacc += etot[e]; }
    for (int e = 0; e < NE; ++e) {
      const int nmt = (etot[e] + 511) >> 9;
      for (int m2 = 0; m2 < nmt && tt < T2MAX; ++m2) tile_tab[tt++] = (e << 16) | m2;
    }
    for (; tt < T2MAX; ++tt) tile_tab[tt] = -1;
#pragma unroll
    for (int e = 0; e < NE; ++e) {
      float d = fsum[e] * (1.f / TOK) - 0.125f;
      l += d * d;
    }
    *loss_out = l * (0.01f / NE);
  }
}

// ---------------- build compacted expert lists + inverse map ----------------
__global__ __launch_bounds__(256) void k_build(const int* __restrict__ tok_e,
    const float* __restrict__ tok_w, const int* __restrict__ prefix,
    const int* __restrict__ blk_off, int* __restrict__ ent, float* __restrict__ entw,
    int* __restrict__ inv) {
  const int t = blockIdx.x * 256 + threadIdx.x;
  const int g = t >> 2;
  const int base = (t & 3) * 2;
  int ee[8];
#pragma unroll
  for (int j = 0; j < 8; ++j) ee[j] = tok_e[g * 8 + j];
#pragma unroll
  for (int s = 0; s < 2; ++s) {
    const int e = ee[base + s];
    int rank = 0;
#pragma unroll
    for (int j = 0; j < 8; ++j) rank += (j < base + s) && (ee[j] == e);
    const int idx = prefix[e] + blk_off[g * NE + e] + rank;
    ent[idx] = t * 2 + s;
    entw[idx] = tok_w[t * 2 + s];
    inv[t * 2 + s] = idx;
  }
}

// ====== GEMM1: 512x64 tile (weights read ONCE), 8 waves, fp32 B inline-cast, depth-2 ======
// LDS/buf (u16 idx): A [0,16384) 512x32, B1 [16384,18432) 64x32, B2 [18432,20480)
__global__ __launch_bounds__(512) void k_gemm1f(const u16* __restrict__ x16,
    const float* __restrict__ w1, const float* __restrict__ w2,
    const float* __restrict__ b1, const float* __restrict__ b2,
    const int* __restrict__ ent, const int* __restrict__ counts,
    const int* __restrict__ prefix, const int* __restrict__ tile_tab,
    u16* __restrict__ act) {
  const int tt = tile_tab[blockIdx.y];
  if (tt < 0) return;
  const int e = tt >> 16, mt = tt & 0xffff, nt = blockIdx.x;   // nt 0..63
  const int cnt = counts[e];
  const int pfx = prefix[e];
  const int tid = threadIdx.x, w = tid >> 6, l = tid & 63;

  __shared__ u16 smem[2][20480];   // 80 KB

  // A staging: 4 rows/thread (q*128 + tid>>2), chunk tid&3 source-swizzled
  const int cA = (tid & 3) ^ ((tid >> 3) & 3);
  const u16* srcA[4]; int dstA[4];
#pragma unroll
  for (int q = 0; q < 4; ++q) {
    const int rr = q * 128 + (tid >> 2);
    int g = mt * 512 + rr; if (g >= cnt) g = cnt - 1;
    srcA[q] = x16 + (size_t)(ent[pfx + g] >> 1) * DIM + cA * 8;
    dstA[q] = q * 4096 + tid * 8;
  }
  // B staging: row rB=tid>>3 (0..63), 4-float chunk cB=tid&7, both tensors
  const int rB = tid >> 3, cB = tid & 7;
  const float* pB1 = w1 + ((size_t)e * HID + nt * 64 + rB) * DIM + cB * 4;
  const float* pB2 = w2 + ((size_t)e * HID + nt * 64 + rB) * DIM + cB * 4;
  const int pos8 = cB ^ (((rB >> 1) & 3) << 1);
  const int wb1 = 16384 + rB * 32 + pos8 * 4;
  const int wb2 = 18432 + rB * 32 + pos8 * 4;

  // fragment reads
  const int xs = ((l >> 4) ^ ((l >> 1) & 3)) * 8;
  const int ra = (w * 64 + (l & 15)) * 32;
  const int rbb = (l & 15) * 32;

  f32x4 acc1[4][4], acc2[4][4];
#pragma unroll
  for (int m = 0; m < 4; ++m)
#pragma unroll
    for (int n = 0; n < 4; ++n) {
      acc1[m][n] = (f32x4){0.f, 0.f, 0.f, 0.f};
      acc2[m][n] = (f32x4){0.f, 0.f, 0.f, 0.f};
    }

  f32x4 a0_, a1_;   // set A: w1, w2
  f32x4 b0_, b1_;   // set B

  auto LOADB = [&](f32x4& r0_, f32x4& r1_, int kt) {
    r0_ = *(const f32x4*)(pB1 + kt * 32);
    r1_ = *(const f32x4*)(pB2 + kt * 32);
  };
  auto STAGEA = [&](int buf, int kt) {
#pragma unroll
    for (int q = 0; q < 4; ++q) gld_lds16(srcA[q] + kt * 32, &smem[buf][dstA[q]]);
  };
  auto WRITEB = [&](int buf, const f32x4& r0_, const f32x4& r1_) {
    u16 u[8];
    u[0] = f2b(r0_[0]); u[1] = f2b(r0_[1]); u[2] = f2b(r0_[2]); u[3] = f2b(r0_[3]);
    u[4] = f2b(r1_[0]); u[5] = f2b(r1_[1]); u[6] = f2b(r1_[2]); u[7] = f2b(r1_[3]);
    *(s16x4*)&smem[buf][wb1] = *(const s16x4*)u;
    *(s16x4*)&smem[buf][wb2] = *(const s16x4*)(u + 4);
  };
  auto MSTEP = [&](int buf) {
    const u16* S = &smem[buf][0];
    s16x8 af[4];
#pragma unroll
    for (int m = 0; m < 4; ++m) af[m] = *(const s16x8*)(S + ra + m * 512 + xs);
    __builtin_amdgcn_s_setprio(1);
#pragma unroll
    for (int n = 0; n < 4; ++n) {
      s16x8 bf1 = *(const s16x8*)(S + 16384 + n * 512 + rbb + xs);
      s16x8 bf2 = *(const s16x8*)(S + 18432 + n * 512 + rbb + xs);
#pragma unroll
      for (int m = 0; m < 4; ++m) {
        acc1[m][n] = __builtin_amdgcn_mfma_f32_16x16x32_bf16(af[m], bf1, acc1[m][n], 0, 0, 0);
        acc2[m][n] = __builtin_amdgcn_mfma_f32_16x16x32_bf16(af[m], bf2, acc2[m][n], 0, 0, 0);
      }
    }
    __builtin_amdgcn_s_setprio(0);
  };

  const int NT = DIM / 32;   // 32
  LOADB(a0_, a1_, 0);
  STAGEA(0, 0);
  LOADB(b0_, b1_, 1);
  asm volatile("s_waitcnt vmcnt(2)" ::: "memory");
  __builtin_amdgcn_sched_barrier(0);
  WRITEB(0, a0_, a1_);
  STAGEA(1, 1);
  asm volatile("s_waitcnt lgkmcnt(0)" ::: "memory");
  __builtin_amdgcn_sched_barrier(0);
  __builtin_amdgcn_s_barrier();

  for (int kt = 0; kt < NT; kt += 2) {
    if (kt + 2 < NT) LOADB(a0_, a1_, kt + 2);
    MSTEP(0);
    __builtin_amdgcn_s_barrier();
    if (kt + 2 < NT) asm volatile("s_waitcnt vmcnt(2)" ::: "memory");
    else             asm volatile("s_waitcnt vmcnt(0)" ::: "memory");
    __builtin_amdgcn_sched_barrier(0);
    WRITEB(1, b0_, b1_);
    if (kt + 2 < NT) STAGEA(0, kt + 2);
    asm volatile("s_waitcnt lgkmcnt(0)" ::: "memory");
    __builtin_amdgcn_sched_barrier(0);
    __builtin_amdgcn_s_barrier();
    if (kt + 3 < NT) LOADB(b0_, b1_, kt + 3);
    MSTEP(1);
    if (kt + 2 < NT) {
      __builtin_amdgcn_s_barrier();
      if (kt + 3 < NT) asm volatile("s_waitcnt vmcnt(2)" ::: "memory");
      else             asm volatile("s_waitcnt vmcnt(0)" ::: "memory");
      __builtin_amdgcn_sched_barrier(0);
      WRITEB(0, a0_, a1_);
      if (kt + 3 < NT) STAGEA(1, kt + 3);
      asm volatile("s_waitcnt lgkmcnt(0)" ::: "memory");
      __builtin_amdgcn_sched_barrier(0);
      __builtin_amdgcn_s_barrier();
    }
  }

#pragma unroll
  for (int n = 0; n < 4; ++n) {
    const int col = nt * 64 + n * 16 + (l & 15);
    const float bb1 = b1[(size_t)e * HID + col];
    const float bb2 = b2[(size_t)e * HID + col];
#pragma unroll
    for (int m = 0; m < 4; ++m) {
#pragma unroll
      for (int r = 0; r < 4; ++r) {
        const int row = mt * 512 + w * 64 + m * 16 + (l >> 4) * 4 + r;
        if (row < cnt) {
          float h = acc1[m][n][r] + bb1;
          float g = acc2[m][n][r] + bb2;
          float a = h * g / (1.f + expf(-g));
          act[(size_t)(pfx + row) * HID + col] = f2b(a);
        }
      }
    }
  }
}

// ====== GEMM2: 512x128 tile, split-K=4 (wp read ONCE), 8 waves, depth-2 ======
// LDS/buf (u16 idx): A [0,16384) 512x32, B [16384,20480) 128x32
__global__ __launch_bounds__(512) void k_gemm2f(const u16* __restrict__ act,
    const float* __restrict__ wp, const float* __restrict__ bp,
    const float* __restrict__ entw, const int* __restrict__ counts,
    const int* __restrict__ prefix, const int* __restrict__ tile_tab,
    float* __restrict__ yp) {
  const int tt = tile_tab[blockIdx.y];
  if (tt < 0) return;
  const int e = tt >> 16, mt = tt & 0xffff;
  const int sk = blockIdx.z, nt = blockIdx.x;   // nt 0..7
  const int cnt = counts[e];
  const int pfx = prefix[e];
  const int tid = threadIdx.x, w = tid >> 6, l = tid & 63;

  __shared__ u16 smem[2][20480];

  const int kbase = sk * (HID / KSPLIT);
  const int cA = (tid & 3) ^ ((tid >> 3) & 3);
  const u16* srcA[4]; int dstA[4];
#pragma unroll
  for (int q = 0; q < 4; ++q) {
    const int rr = q * 128 + (tid >> 2);
    int g = mt * 512 + rr; if (g >= cnt) g = cnt - 1;
    srcA[q] = act + (size_t)(pfx + g) * HID + kbase + cA * 8;
    dstA[q] = q * 4096 + tid * 8;
  }
  // B staging: row rB=tid>>2 (0..127), 8 floats at (tid&3)*8
  const int rB = tid >> 2;
  const float* pB = wp + ((size_t)e * DIM + nt * 128 + rB) * HID + kbase + (tid & 3) * 8;
  const int c0 = ((tid & 3) * 2) ^ (((rB >> 1) & 3) << 1);
  const int c1 = ((tid & 3) * 2 + 1) ^ (((rB >> 1) & 3) << 1);
  const int wbB = 16384 + rB * 32;

  const int xs = ((l >> 4) ^ ((l >> 1) & 3)) * 8;
  const int ra = (w * 64 + (l & 15)) * 32;
  const int rbb = (l & 15) * 32;

  f32x4 acc[4][8];
#pragma unroll
  for (int m = 0; m < 4; ++m)
#pragma unroll
    for (int n = 0; n < 8; ++n) acc[m][n] = (f32x4){0.f, 0.f, 0.f, 0.f};

  f32x4 a0_, a1_;
  f32x4 b0_, b1_;

  auto LOADB = [&](f32x4& r0_, f32x4& r1_, int kt) {
    r0_ = *(const f32x4*)(pB + kt * 32);
    r1_ = *(const f32x4*)(pB + kt * 32 + 4);
  };
  auto STAGEA = [&](int buf, int kt) {
#pragma unroll
    for (int q = 0; q < 4; ++q) gld_lds16(srcA[q] + kt * 32, &smem[buf][dstA[q]]);
  };
  auto WRITEB = [&](int buf, const f32x4& r0_, const f32x4& r1_) {
    u16 u[8];
    u[0] = f2b(r0_[0]); u[1] = f2b(r0_[1]); u[2] = f2b(r0_[2]); u[3] = f2b(r0_[3]);
    u[4] = f2b(r1_[0]); u[5] = f2b(r1_[1]); u[6] = f2b(r1_[2]); u[7] = f2b(r1_[3]);
    *(s16x4*)&smem[buf][wbB + c0 * 4] = *(const s16x4*)u;
    *(s16x4*)&smem[buf][wbB + c1 * 4] = *(const s16x4*)(u + 4);
  };
  auto MSTEP = [&](int buf) {
    const u16* S = &smem[buf][0];
    s16x8 af[4];
#pragma unroll
    for (int m = 0; m < 4; ++m) af[m] = *(const s16x8*)(S + ra + m * 512 + xs);
    __builtin_amdgcn_s_setprio(1);
#pragma unroll
    for (int n = 0; n < 8; ++n) {
      s16x8 bf = *(const s16x8*)(S + 16384 + n * 512 + rbb + xs);
#pragma unroll
      for (int m = 0; m < 4; ++m)
        acc[m][n] = __builtin_amdgcn_mfma_f32_16x16x32_bf16(af[m], bf, acc[m][n], 0, 0, 0);
    }
    __builtin_amdgcn_s_setprio(0);
  };

  const int NT = HID / KSPLIT / 32;   // 32
  LOADB(a0_, a1_, 0);
  STAGEA(0, 0);
  LOADB(b0_, b1_, 1);
  asm volatile("s_waitcnt vmcnt(2)" ::: "memory");
  __builtin_amdgcn_sched_barrier(0);
  WRITEB(0, a0_, a1_);
  STAGEA(1, 1);
  asm volatile("s_waitcnt lgkmcnt(0)" ::: "memory");
  __builtin_amdgcn_sched_barrier(0);
  __builtin_amdgcn_s_barrier();

  for (int kt = 0; kt < NT; kt += 2) {
    if (kt + 2 < NT) LOADB(a0_, a1_, kt + 2);
    MSTEP(0);
    __builtin_amdgcn_s_barrier();
    if (kt + 2 < NT) asm volatile("s_waitcnt vmcnt(2)" ::: "memory");
    else             asm volatile("s_waitcnt vmcnt(0)" ::: "memory");
    __builtin_amdgcn_sched_barrier(0);
    WRITEB(1, b0_, b1_);
    if (kt + 2 < NT) STAGEA(0, kt + 2);
    asm volatile("s_waitcnt lgkmcnt(0)" ::: "memory");
    __builtin_amdgcn_sched_barrier(0);
    __builtin_amdgcn_s_barrier();
    if (kt + 3 < NT) LOADB(b0_, b1_, kt + 3);
    MSTEP(1);
    if (kt + 2 < NT) {
      __builtin_amdgcn_s_barrier();
      if (kt + 3 < NT) asm volatile("s_waitcnt vmcnt(2)" ::: "memory");
      else             asm volatile("s_waitcnt vmcnt(0)" ::: "memory");
      __builtin_amdgcn_sched_barrier(0);
      WRITEB(0, a0_, a1_);
      if (kt + 3 < NT) STAGEA(1, kt + 3);
      asm volatile("s_waitcnt lgkmcnt(0)" ::: "memory");
      __builtin_amdgcn_sched_barrier(0);
      __builtin_amdgcn_s_barrier();
    }
  }

#pragma unroll
  for (int n = 0; n < 8; ++n) {
    const int col = nt * 128 + n * 16 + (l & 15);
    const float bpv = (sk == 0) ? bp[(size_t)e * DIM + col] : 0.f;
#pragma unroll
    for (int m = 0; m < 4; ++m) {
#pragma unroll
      for (int r = 0; r < 4; ++r) {
        const int row = mt * 512 + w * 64 + m * 16 + (l >> 4) * 4 + r;
        if (row < cnt) {
          const int idx = pfx + row;
          yp[((size_t)sk * (TOK * 2) + idx) * DIM + col] = entw[idx] * (acc[m][n][r] + bpv);
        }
      }
    }
  }
}

// ---------------- final: out[t] = sum over 2 slots x KSPLIT partials ----------------
__global__ __launch_bounds__(256) void k_final(const float* __restrict__ yp,
    const int* __restrict__ inv, float* __restrict__ out) {
  const int t = blockIdx.x;
  const int d = threadIdx.x * 4;
  const int i0 = inv[t * 2], i1 = inv[t * 2 + 1];
  float4 s = {0.f, 0.f, 0.f, 0.f};
#pragma unroll
  for (int sk = 0; sk < KSPLIT; ++sk) {
    float4 a = *(const float4*)(yp + ((size_t)sk * (TOK * 2) + i0) * DIM + d);
    float4 b = *(const float4*)(yp + ((size_t)sk * (TOK * 2) + i1) * DIM + d);
    s.x += a.x + b.x; s.y += a.y + b.y; s.z += a.z + b.z; s.w += a.w + b.w;
  }
  *(float4*)(out + (size_t)t * DIM + d) = s;
}

extern "C" void kernel_launch(void* const* d_in, const int* in_sizes, int n_in,
                              void* d_out, int out_size, void* d_ws, size_t ws_size,
                              hipStream_t stream) {
  const float* x      = (const float*)d_in[0];
  const float* noise  = (const float*)d_in[1];
  const float* gate_w = (const float*)d_in[2];
  const float* nw     = (const float*)d_in[3];
  const float* w1     = (const float*)d_in[4];
  const float* b1     = (const float*)d_in[5];
  const float* w2     = (const float*)d_in[6];
  const float* b2     = (const float*)d_in[7];
  const float* wp     = (const float*)d_in[8];
  const float* bp     = (const float*)d_in[9];
  float* out = (float*)d_out;
  char* ws = (char*)d_ws;

  const size_t SZ_X16 = (size_t)TOK * DIM * 2;
  const size_t SZ_ACT = (size_t)TOK * 2 * HID * 2;
  const size_t SZ_YP  = (size_t)KSPLIT * TOK * 2 * DIM * 4;

  u16* x16  = (u16*)ws;
  u16* act  = (u16*)(ws + SZ_X16);
  float* yp = (float*)(ws + SZ_X16 + SZ_ACT);
  char* meta = ws + SZ_X16 + SZ_ACT + SZ_YP;
  int*   tok_e    = (int*)(meta);
  float* tok_w    = (float*)(meta + 16384);
  int*   ent      = (int*)(meta + 32768);
  float* entw     = (float*)(meta + 49152);
  int*   bhist    = (int*)(meta + 65536);
  float* bgw      = (float*)(meta + 81920);
  int*   blk_off  = (int*)(meta + 98304);
  int*   inv      = (int*)(meta + 114688);
  int*   counts   = (int*)(meta + 131072);
  int*   prefix   = (int*)(meta + 131072 + 64);
  int*   tile_tab = (int*)(meta + 131072 + 128);

  k_gate<<<TOK / 4, 256, 0, stream>>>(x, noise, gate_w, nw, tok_e, tok_w, bhist, bgw, x16);
  k_scan<<<1, 512, 0, stream>>>(bhist, bgw, blk_off, prefix, counts, tile_tab,
                                out + (size_t)TOK * DIM);
  k_build<<<TOK / 256, 256, 0, stream>>>(tok_e, tok_w, prefix, blk_off, ent, entw, inv);
  k_gemm1f<<<dim3(HID / 64, T2MAX), 512, 0, stream>>>(x16, w1, w2, b1, b2, ent,
                                                      counts, prefix, tile_tab, act);
  k_gemm2f<<<dim3(DIM / 128, T2MAX, KSPLIT), 512, 0, stream>>>(act, wp, bp, entw,
                                                               counts, prefix, tile_tab, yp);
  k_final<<<TOK, 256, 0, stream>>>(yp, inv, out);
}